// Round 1
// baseline (443.342 us; speedup 1.0000x reference)
//
#include <hip/hip_runtime.h>
#include <stdint.h>

// Problem constants (from reference): B=4, I=32, N=4096, D=64, TEM=1.0, WP=0.5
#define Bsz 4
#define Isz 32
#define Nsz 4096
#define Dsz 64
#define WPc 0.5f

#define TM 64
#define TN 64

// ---------------------------------------------------------------------------
// Kernel 1: decode one-hot bool label [B,I,N] -> inst[b,n] (instance id) and
// cnt[b,i] (points per instance). label is a partition (exactly one i true).
// ---------------------------------------------------------------------------
__global__ __launch_bounds__(256) void prep_kernel(
    const uint8_t* __restrict__ label, int* __restrict__ inst,
    int* __restrict__ cnt) {
  int b = blockIdx.x;
  const uint8_t* lb = label + (size_t)b * Isz * Nsz;
  for (int n = threadIdx.x; n < Nsz; n += blockDim.x) {
    int id = 0;
#pragma unroll
    for (int i = 0; i < Isz; ++i) {
      if (lb[(size_t)i * Nsz + n]) id = i;
    }
    inst[b * Nsz + n] = id;
    atomicAdd(&cnt[b * Isz + id], 1);
  }
}

// ---------------------------------------------------------------------------
// Kernel 2: fused sim-tile + epilogue.
// Each block computes a TM x TN tile of sim = x[b] @ x[b]^T (K = D = 64),
// then per element: same-instance -> (s-1)^2 into row pos-accum,
//                   diff-instance -> exp(s)  into row neg-accum.
// Row partials reduced in LDS, then atomicAdd'd to global per-row arrays.
// Thread layout: 16x16 threads, each computes a 4x4 register tile.
// ---------------------------------------------------------------------------
__global__ __launch_bounds__(256) void sim_kernel(
    const float* __restrict__ x, const int* __restrict__ inst,
    float* __restrict__ gpos, float* __restrict__ gneg) {
  __shared__ float sA[Dsz * TM];  // [d][r] transposed
  __shared__ float sB[Dsz * TN];  // [d][c] transposed
  __shared__ int sIr[TM];
  __shared__ int sIc[TN];
  __shared__ float sPos[TM];
  __shared__ float sNeg[TM];

  const int tx = threadIdx.x;  // 0..15 (cols)
  const int ty = threadIdx.y;  // 0..15 (rows)
  const int t = ty * 16 + tx;  // 0..255

  const int b = blockIdx.y / (Nsz / TM);
  const int rt = blockIdx.y % (Nsz / TM);
  const int ct = blockIdx.x;
  const int row0 = rt * TM;
  const int col0 = ct * TN;
  const float* xb = x + (size_t)b * Nsz * Dsz;

  // Stage tiles, transposing to [d][point] layout.
  // 256 threads: thread t handles point r = t&63, d-range (t>>6)*16..+15.
  {
    const int r = t & 63;
    const int d0 = (t >> 6) * 16;
    const float* srcA = xb + (size_t)(row0 + r) * Dsz + d0;
    const float* srcB = xb + (size_t)(col0 + r) * Dsz + d0;
#pragma unroll
    for (int k = 0; k < 16; k += 4) {
      float4 v = *(const float4*)(srcA + k);
      sA[(d0 + k + 0) * TM + r] = v.x;
      sA[(d0 + k + 1) * TM + r] = v.y;
      sA[(d0 + k + 2) * TM + r] = v.z;
      sA[(d0 + k + 3) * TM + r] = v.w;
      float4 w = *(const float4*)(srcB + k);
      sB[(d0 + k + 0) * TN + r] = w.x;
      sB[(d0 + k + 1) * TN + r] = w.y;
      sB[(d0 + k + 2) * TN + r] = w.z;
      sB[(d0 + k + 3) * TN + r] = w.w;
    }
  }
  if (t < TM) {
    sIr[t] = inst[b * Nsz + row0 + t];
    sPos[t] = 0.f;
    sNeg[t] = 0.f;
  } else if (t < TM + TN) {
    const int c = t - TM;
    sIc[c] = inst[b * Nsz + col0 + c];
  }
  __syncthreads();

  float acc[4][4];
#pragma unroll
  for (int i = 0; i < 4; ++i)
#pragma unroll
    for (int j = 0; j < 4; ++j) acc[i][j] = 0.f;

#pragma unroll 16
  for (int d = 0; d < Dsz; ++d) {
    float4 a = *(const float4*)&sA[d * TM + ty * 4];
    float4 c = *(const float4*)&sB[d * TN + tx * 4];
    acc[0][0] += a.x * c.x; acc[0][1] += a.x * c.y;
    acc[0][2] += a.x * c.z; acc[0][3] += a.x * c.w;
    acc[1][0] += a.y * c.x; acc[1][1] += a.y * c.y;
    acc[1][2] += a.y * c.z; acc[1][3] += a.y * c.w;
    acc[2][0] += a.z * c.x; acc[2][1] += a.z * c.y;
    acc[2][2] += a.z * c.z; acc[2][3] += a.z * c.w;
    acc[3][0] += a.w * c.x; acc[3][1] += a.w * c.y;
    acc[3][2] += a.w * c.z; acc[3][3] += a.w * c.w;
  }

  // Epilogue: classify each element, accumulate per-row partials.
  int ic[4];
#pragma unroll
  for (int j = 0; j < 4; ++j) ic[j] = sIc[tx * 4 + j];

#pragma unroll
  for (int i = 0; i < 4; ++i) {
    const int ir = sIr[ty * 4 + i];
    float p = 0.f, ng = 0.f;
#pragma unroll
    for (int j = 0; j < 4; ++j) {
      const float s = acc[i][j];
      if (ic[j] == ir) {
        const float dlt = s - 1.f;
        p += dlt * dlt;
      } else {
        ng += __expf(s);  // TEM == 1.0
      }
    }
    atomicAdd(&sPos[ty * 4 + i], p);
    atomicAdd(&sNeg[ty * 4 + i], ng);
  }
  __syncthreads();
  if (t < TM) {
    atomicAdd(&gpos[b * Nsz + row0 + t], sPos[t]);
    atomicAdd(&gneg[b * Nsz + row0 + t], sNeg[t]);
  }
}

// ---------------------------------------------------------------------------
// Kernel 3: finalize. Per row p: i=inst[p], c=cnt[i]; if c>=5:
//   contrib = WP * pos/c^2 + (1-WP) * log(max(neg,1e-30))/c
// Sum all rows, divide by B*I, write scalar out.
// ---------------------------------------------------------------------------
__global__ __launch_bounds__(1024) void fin_kernel(
    const float* __restrict__ gpos, const float* __restrict__ gneg,
    const int* __restrict__ inst, const int* __restrict__ cnt,
    float* __restrict__ out) {
  __shared__ float red[16];
  const int t = threadIdx.x;
  float local = 0.f;
  for (int idx = t; idx < Bsz * Nsz; idx += 1024) {
    const int b = idx >> 12;  // / Nsz
    const int i = inst[idx];
    const float c = (float)cnt[b * Isz + i];
    if (c >= 5.f) {
      const float lp = gpos[idx] / (c * c);
      const float ln = __logf(fmaxf(gneg[idx], 1e-30f)) / c;
      local += WPc * lp + (1.f - WPc) * ln;
    }
  }
#pragma unroll
  for (int o = 32; o > 0; o >>= 1) local += __shfl_down(local, o, 64);
  if ((t & 63) == 0) red[t >> 6] = local;
  __syncthreads();
  if (t < 16) {
    float v = red[t];
#pragma unroll
    for (int o = 8; o > 0; o >>= 1) v += __shfl_down(v, o, 16);
    if (t == 0) out[0] = v / (float)(Bsz * Isz);
  }
}

// ---------------------------------------------------------------------------
extern "C" void kernel_launch(void* const* d_in, const int* in_sizes, int n_in,
                              void* d_out, int out_size, void* d_ws,
                              size_t ws_size, hipStream_t stream) {
  const float* x = (const float*)d_in[0];          // [B,N,D] fp32
  const uint8_t* label = (const uint8_t*)d_in[1];  // [B,I,N] bool (1B/elem)
  float* out = (float*)d_out;

  // Workspace layout
  float* gpos = (float*)d_ws;                // B*N floats
  float* gneg = gpos + Bsz * Nsz;            // B*N floats
  int* inst = (int*)(gneg + Bsz * Nsz);      // B*N ints
  int* cnt = inst + Bsz * Nsz;               // B*I ints
  const size_t zbytes =
      sizeof(float) * (size_t)Bsz * Nsz * 2 +
      sizeof(int) * ((size_t)Bsz * Nsz + (size_t)Bsz * Isz);
  hipMemsetAsync(d_ws, 0, zbytes, stream);

  prep_kernel<<<Bsz, 256, 0, stream>>>(label, inst, cnt);

  dim3 grid(Nsz / TN, Bsz * (Nsz / TM));
  sim_kernel<<<grid, dim3(16, 16), 0, stream>>>(x, inst, gpos, gneg);

  fin_kernel<<<1, 1024, 0, stream>>>(gpos, gneg, inst, cnt, out);
}

// Round 2
// 123.778 us; speedup vs baseline: 3.5818x; 3.5818x over previous
//
#include <hip/hip_runtime.h>
#include <stdint.h>

// Problem constants: B=4, I=32, N=4096, D=64, TEM=1.0, WP=0.5
#define Bsz 4
#define Isz 32
#define Nsz 4096
#define Dsz 64
#define WPc 0.5f

typedef __attribute__((ext_vector_type(8))) short short8;   // 8 bf16 = 4 VGPRs
typedef __attribute__((ext_vector_type(4))) float floatx4;  // MFMA C/D

__device__ inline uint16_t f2bf(float f) {
  uint32_t u = __float_as_uint(f);
  u += 0x7fffu + ((u >> 16) & 1u);  // round-to-nearest-even
  return (uint16_t)(u >> 16);
}

// ---------------------------------------------------------------------------
// Kernel 0: fp32 x -> bf16 xb. 4 elems/thread, 1M elems total.
// ---------------------------------------------------------------------------
__global__ __launch_bounds__(256) void cvt_kernel(const float* __restrict__ x,
                                                  uint16_t* __restrict__ xb) {
  const int idx = (blockIdx.x * 256 + threadIdx.x) * 4;
  const float4 v = *(const float4*)(x + idx);
  ushort4 o;
  o.x = f2bf(v.x);
  o.y = f2bf(v.y);
  o.z = f2bf(v.z);
  o.w = f2bf(v.w);
  *(ushort4*)(xb + idx) = o;
}

// ---------------------------------------------------------------------------
// Kernel 1: decode one-hot bool label [B,I,N] -> inst[b,n], cnt[b,i].
// One thread per point; per-block LDS count reduction.
// ---------------------------------------------------------------------------
__global__ __launch_bounds__(256) void prep_kernel(
    const uint8_t* __restrict__ label, int* __restrict__ inst,
    int* __restrict__ cnt) {
  __shared__ int scnt[Isz];
  const int b = blockIdx.x >> 4;
  const int n = (blockIdx.x & 15) * 256 + threadIdx.x;
  if (threadIdx.x < Isz) scnt[threadIdx.x] = 0;
  __syncthreads();
  const uint8_t* lb = label + (size_t)b * Isz * Nsz;
  int id = 0;
#pragma unroll
  for (int i = 0; i < Isz; ++i) {
    if (lb[(size_t)i * Nsz + n]) id = i;
  }
  inst[b * Nsz + n] = id;
  atomicAdd(&scnt[id], 1);
  __syncthreads();
  if (threadIdx.x < Isz) atomicAdd(&cnt[b * Isz + threadIdx.x], scnt[threadIdx.x]);
}

// ---------------------------------------------------------------------------
// Kernel 2: MFMA sim tile + fused epilogue.
// Block = 256 thr = 4 waves; block tile 128x128 of sim = X X^T (K=D=64).
// Wave w covers rows w*32..w*32+31 (2 row-tiles x 8 col-tiles of 16x16).
// Fragments load DIRECTLY from global bf16 (L2-resident, no LDS staging):
//   A/B lane layout: [m = lane&15][k = (lane>>4)*8 + j] -> contiguous 16B.
// Epilogue classifies each sim element via instance ids, accumulates per-row
// pos=(s-1)^2 / neg=exp(s) partials; cross-lane reduce (xor 1,2,4,8 within
// 16-lane groups); per-block LDS row accum; one global atomicAdd per row.
// C/D layout: col = lane&15, row = (lane>>4)*4 + reg   [verified m89/m91].
// ---------------------------------------------------------------------------
__global__ __launch_bounds__(256) void sim_mfma(
    const uint16_t* __restrict__ xb, const int* __restrict__ inst,
    float* __restrict__ gpos, float* __restrict__ gneg) {
  __shared__ int sIr[128];
  __shared__ int sIc[128];
  __shared__ float sPos[128];
  __shared__ float sNeg[128];

  const int t = threadIdx.x;
  const int lane = t & 63;
  const int w = t >> 6;
  const int quad = lane >> 4;
  const int l15 = lane & 15;

  const int b = blockIdx.z;
  const int row0 = blockIdx.y * 128;
  const int col0 = blockIdx.x * 128;
  const size_t bN = (size_t)b * Nsz;

  if (t < 128) {
    sIr[t] = inst[bN + row0 + t];
    sPos[t] = 0.f;
    sNeg[t] = 0.f;
  } else {
    const int c = t - 128;
    sIc[c] = inst[bN + col0 + c];
  }
  __syncthreads();

  const int wrow0 = row0 + w * 32;
  const uint16_t* xbB = xb + bN * Dsz;

  floatx4 acc[2][8];
#pragma unroll
  for (int rt = 0; rt < 2; ++rt)
#pragma unroll
    for (int ct = 0; ct < 8; ++ct) acc[rt][ct] = (floatx4){0.f, 0.f, 0.f, 0.f};

#pragma unroll
  for (int kh = 0; kh < 2; ++kh) {
    const int ko = quad * 8 + kh * 32;
    short8 af[2], bf[8];
#pragma unroll
    for (int rt = 0; rt < 2; ++rt)
      af[rt] = *(const short8*)(xbB + (size_t)(wrow0 + rt * 16 + l15) * Dsz + ko);
#pragma unroll
    for (int ct = 0; ct < 8; ++ct)
      bf[ct] = *(const short8*)(xbB + (size_t)(col0 + ct * 16 + l15) * Dsz + ko);
#pragma unroll
    for (int ct = 0; ct < 8; ++ct)
#pragma unroll
      for (int rt = 0; rt < 2; ++rt)
        acc[rt][ct] = __builtin_amdgcn_mfma_f32_16x16x32_bf16(af[rt], bf[ct],
                                                              acc[rt][ct], 0, 0, 0);
  }

  // Epilogue
  int myc[8];
#pragma unroll
  for (int ct = 0; ct < 8; ++ct) myc[ct] = sIc[ct * 16 + l15];

#pragma unroll
  for (int rt = 0; rt < 2; ++rt) {
    const int rl = w * 32 + rt * 16 + quad * 4;
    int ir[4];
#pragma unroll
    for (int r = 0; r < 4; ++r) ir[r] = sIr[rl + r];
    float ps[4] = {0.f, 0.f, 0.f, 0.f};
    float ng[4] = {0.f, 0.f, 0.f, 0.f};
#pragma unroll
    for (int ct = 0; ct < 8; ++ct) {
      const int ci = myc[ct];
      const floatx4 v = acc[rt][ct];
#pragma unroll
      for (int r = 0; r < 4; ++r) {
        const float s = v[r];
        const float d = s - 1.f;
        const bool same = (ci == ir[r]);
        ps[r] += same ? d * d : 0.f;
        ng[r] += same ? 0.f : __expf(s);  // TEM == 1.0
      }
    }
#pragma unroll
    for (int r = 0; r < 4; ++r) {
      float p = ps[r], q = ng[r];
#pragma unroll
      for (int m = 1; m < 16; m <<= 1) {
        p += __shfl_xor(p, m, 64);
        q += __shfl_xor(q, m, 64);
      }
      if (l15 == 0) {  // unique (w,rt,quad,reg) -> unique row: no atomic needed
        sPos[rl + r] += p;
        sNeg[rl + r] += q;
      }
    }
  }
  __syncthreads();
  if (t < 128) {
    atomicAdd(&gpos[bN + row0 + t], sPos[t]);
    atomicAdd(&gneg[bN + row0 + t], sNeg[t]);
  }
}

// ---------------------------------------------------------------------------
// Kernel 3: finalize -> scalar loss.
// ---------------------------------------------------------------------------
__global__ __launch_bounds__(1024) void fin_kernel(
    const float* __restrict__ gpos, const float* __restrict__ gneg,
    const int* __restrict__ inst, const int* __restrict__ cnt,
    float* __restrict__ out) {
  __shared__ float red[16];
  const int t = threadIdx.x;
  float local = 0.f;
  for (int idx = t; idx < Bsz * Nsz; idx += 1024) {
    const int b = idx >> 12;  // / Nsz
    const int i = inst[idx];
    const float c = (float)cnt[b * Isz + i];
    if (c >= 5.f) {
      const float lp = gpos[idx] / (c * c);
      const float ln = __logf(fmaxf(gneg[idx], 1e-30f)) / c;
      local += WPc * lp + (1.f - WPc) * ln;
    }
  }
#pragma unroll
  for (int o = 32; o > 0; o >>= 1) local += __shfl_down(local, o, 64);
  if ((t & 63) == 0) red[t >> 6] = local;
  __syncthreads();
  if (t < 16) {
    float v = red[t];
#pragma unroll
    for (int o = 8; o > 0; o >>= 1) v += __shfl_down(v, o, 16);
    if (t == 0) out[0] = v / (float)(Bsz * Isz);
  }
}

// ---------------------------------------------------------------------------
extern "C" void kernel_launch(void* const* d_in, const int* in_sizes, int n_in,
                              void* d_out, int out_size, void* d_ws,
                              size_t ws_size, hipStream_t stream) {
  const float* x = (const float*)d_in[0];          // [B,N,D] fp32
  const uint8_t* label = (const uint8_t*)d_in[1];  // [B,I,N] bool
  float* out = (float*)d_out;

  // Workspace layout: [gpos BN f32][gneg BN f32][cnt B*I i32][inst BN i32][xb BND bf16]
  float* gpos = (float*)d_ws;
  float* gneg = gpos + Bsz * Nsz;
  int* cnt = (int*)(gneg + Bsz * Nsz);
  int* inst = cnt + Bsz * Isz;
  uint16_t* xb = (uint16_t*)(inst + Bsz * Nsz);

  // Zero gpos+gneg+cnt (contiguous prefix).
  const size_t zbytes = sizeof(float) * ((size_t)Bsz * Nsz * 2 + Bsz * Isz);
  hipMemsetAsync(d_ws, 0, zbytes, stream);

  cvt_kernel<<<(Bsz * Nsz * Dsz) / (256 * 4), 256, 0, stream>>>(x, xb);
  prep_kernel<<<Bsz * 16, 256, 0, stream>>>(label, inst, cnt);

  dim3 grid(Nsz / 128, Nsz / 128, Bsz);
  sim_mfma<<<grid, 256, 0, stream>>>(xb, inst, gpos, gneg);

  fin_kernel<<<1, 1024, 0, stream>>>(gpos, gneg, inst, cnt, out);
}